// Round 13
// baseline (284.206 us; speedup 1.0000x reference)
//
#include <hip/hip_runtime.h>

#define N_NODES 100000
#define N_EDGES 3200000
#define EPS 1e-5f
#define NODE_BLOCKS 391   // ceil(100000/256)
#define NB 782            // buckets of 128 nodes (dst >> 7)
#define BSTRIDE 4608      // fixed bucket region: mean 4096 + 8 sigma
#define NSUB 3            // chunks of 1536 slots per bucket (3*1536 = 4608)
#define S1_EPB 8192
#define S1_BLOCKS 391

typedef unsigned int uint;
typedef uint u32x2 __attribute__((ext_vector_type(2)));
typedef uint u32x4 __attribute__((ext_vector_type(4)));
typedef _Float16 f16x8 __attribute__((ext_vector_type(8)));
typedef float f32x16 __attribute__((ext_vector_type(16)));

static __device__ __forceinline__ f16x8 as_h8(u32x4 u) { return __builtin_bit_cast(f16x8, u); }
static __device__ __forceinline__ uint pkh(float a, float b) {
    return __builtin_bit_cast(uint, __builtin_amdgcn_cvt_pkrtz(a, b));
}
// v_permlane32_swap_b32: a' = [a.lo32 | b.lo32], b' = [a.hi32 | b.hi32].
// R13: use the MODELED intrinsic instead of `asm volatile` — volatile asm is a
// machine-scheduler barrier (8 per tile) that serialized the whole tile chain
// and defeated every ILP/occupancy intervention (R3,R5-R8 nulls). The builtin
// is convergent + scheduler-visible: safe (unlike R5's raw non-volatile asm,
// which got duplicated/sunk) and reorderable. Callers are wave-uniform, so
// fi=false, bound_ctrl=false is exact.
static __device__ __forceinline__ void swap32(uint& a, uint& b) {
#if __has_builtin(__builtin_amdgcn_permlane32_swap)
    u32x2 r = __builtin_amdgcn_permlane32_swap(a, b, false, false);
    a = r.x; b = r.y;
#else
    asm volatile("v_permlane32_swap_b32 %0, %1" : "+v"(a), "+v"(b));
#endif
}
// packed f16 relu: max(x, 0) on both halves. rtz-then-relu == relu-then-rtz.
static __device__ __forceinline__ uint prelu(uint u, uint z) {
    uint r;
    asm("v_pk_max_f16 %0, %1, %2" : "=v"(r) : "v"(u), "v"(z));
    return r;
}

#define MFMA(A, B, C) __builtin_amdgcn_mfma_f32_32x32x16_f16(as_h8(A), as_h8(B), (C), 0, 0, 0)

// Repack MFMA C (32 rows x 32 edge-cols, row=(r&3)+8*(r>>2)+4*hi) into the two
// B-fragments for the next K=32 MFMA pair, applying relu in packed f16.
static __device__ __forceinline__ void repack(const f32x16& c, u32x4& f0, u32x4& f1, uint z) {
    uint p0 = prelu(pkh(c[0], c[1]), z),   p1 = prelu(pkh(c[2], c[3]), z);
    uint q0 = prelu(pkh(c[4], c[5]), z),   q1 = prelu(pkh(c[6], c[7]), z);
    uint p2 = prelu(pkh(c[8], c[9]), z),   p3 = prelu(pkh(c[10], c[11]), z);
    uint q2 = prelu(pkh(c[12], c[13]), z), q3 = prelu(pkh(c[14], c[15]), z);
    swap32(p0, q0); swap32(p1, q1);
    swap32(p2, q2); swap32(p3, q3);
    f0.x = p0; f0.y = p1; f0.z = q0; f0.w = q1;
    f1.x = p2; f1.y = p3; f1.z = q2; f1.w = q3;
}

static __device__ __forceinline__ void decode4(const int4& q, int* ss, int* ia) {
    int e0 = q.x, e1 = q.y, e2 = q.z, e3 = q.w;
    ss[0] = e0 & 0x1FFFF; ia[0] = (e0 >> 17) & 127;
    ss[1] = e1 & 0x1FFFF; ia[1] = (e1 >> 17) & 127;
    ss[2] = e2 & 0x1FFFF; ia[2] = (e2 >> 17) & 127;
    ss[3] = e3 & 0x1FFFF; ia[3] = (e3 >> 17) & 127;
    #pragma unroll
    for (int k = 0; k < 4; k++)
        if (ss[k] >= N_NODES) ss[k] = 0;   // slots >= cb hold stale garbage
}

// ---- workspace layout (bytes) ----
#define OFF_STATS  0          // 8 doubles (bn sums)          [zeroed]
#define OFF_BCNT   1024       // int[782] bucket counts       [zeroed]
#define OFF_INVCNT 5120       // float[100000]
#define OFF_AGG1   405120     // float2[100000]
#define OFF_DECW   1205120    // dec MFMA tables: 2112 dwords = 8448B
#define OFF_BUCKET 1214848    // int[782*4608] packed entries s|(dloc<<17) (14.4 MB)
#define OFF_PENC   15629696   // float2[782*3*128] enc partials (2.4 MB)
#define OFF_PCNT   22836608   // int[782*3*128]   count partials (1.2 MB)
#define OFF_PDEC   26440064   // float4[782*3*128] dec partials (4.8 MB)
#define OFF_ENCW   26440064   // enc tables alias pdec head (dead before k_dec writes)

// table layout (dword offsets), identical enc/dec:
//   [0,256)      W1 hi (+bias row: enc k=8, dec k=4)
//   [256,512)    W1 lo (+bias residual row)
//   [512,768)    W2 hi k-tile0   [768,1024)  W2 hi k-tile1
//   [1024,1280)  W2 lo k-tile0   [1280,1536) W2 lo k-tile1
//   [1536,1792)  W3 k-tile0      [1792,2048) W3 k-tile1  (hi only; rows remapped)
//   [2048,2080)  b2 C-frag tab (f32, [hi*16+r])
//   [2080,2112)  b3 tab (remapped rows)

// hi/lo f16 split: part 0 = f16(v), part 1 = f16(v - f16(v)); packs a pair.
static __device__ __forceinline__ uint pk_part(float a, float b, int part) {
    _Float16 ah = (_Float16)a, bh = (_Float16)b;
    if (part) {
        a -= (float)ah; b -= (float)bh;
        ah = (_Float16)a; bh = (_Float16)b;
    }
    return (uint)__builtin_bit_cast(unsigned short, ah) |
           ((uint)__builtin_bit_cast(unsigned short, bh) << 16);
}

// Build all MFMA fragment tables (R8/R10-verified). A[m][k]: m=lane&31, k=8*hi+e.
// L1 bias rides a weight ROW: enc A[m][8]=BN-folded b1, dec A[m][4]=db1.
// W3 rows remapped for split atomics; W3 hi-part only.
__global__ __launch_bounds__(256) void k_prep(const double* __restrict__ stats,
                                              const float* __restrict__ bn_w,
                                              const float* __restrict__ bn_b,
                                              const float* __restrict__ ew1,
                                              const float* __restrict__ eb1,
                                              const float* __restrict__ ew2,
                                              const float* __restrict__ eb2,
                                              const float* __restrict__ ew3,
                                              const float* __restrict__ eb3,
                                              const float* __restrict__ dw1,
                                              const float* __restrict__ db1,
                                              const float* __restrict__ dw2,
                                              const float* __restrict__ db2,
                                              const float* __restrict__ dw3,
                                              const float* __restrict__ db3,
                                              uint* __restrict__ encw,
                                              uint* __restrict__ decw) {
    int t = threadIdx.x;
    int lane = t >> 2, d = t & 3;
    int hi = lane >> 5, m = lane & 31;

    const double inv_n = 1.0 / (double)N_NODES;
    float sc[4], sh[4];
    #pragma unroll
    for (int dd = 0; dd < 4; dd++) {
        double mu = stats[dd] * inv_n;
        double vr = stats[4 + dd] * inv_n - mu * mu;
        float rs = (float)(1.0 / sqrt(vr + (double)EPS));
        sc[dd] = rs * bn_w[dd];
        sh[dd] = bn_b[dd] - (float)mu * sc[dd];
    }
    float b1p = eb1[m];
    #pragma unroll
    for (int dd = 0; dd < 4; dd++) b1p += ew1[dd * 32 + m] * sh[dd];

    int k0 = 8 * hi + 2 * d;
    {   // enc W1 hi+lo (BN-folded weights) + bias row k=8
        float v0 = (k0 < 8) ? ew1[k0 * 32 + m] * sc[k0 & 3]
                            : (k0 == 8 ? b1p : 0.f);
        float v1 = (k0 + 1 < 8) ? ew1[(k0 + 1) * 32 + m] * sc[(k0 + 1) & 3] : 0.f;
        encw[t] = pk_part(v0, v1, 0);
        encw[256 + t] = pk_part(v0, v1, 1);
    }
    {   // dec W1 hi+lo + bias row k=4
        float v0 = (k0 < 4) ? dw1[k0 * 32 + m] : (k0 == 4 ? db1[m] : 0.f);
        float v1 = (k0 + 1 < 4) ? dw1[(k0 + 1) * 32 + m] : 0.f;
        decw[t] = pk_part(v0, v1, 0);
        decw[256 + t] = pk_part(v0, v1, 1);
    }
    #pragma unroll
    for (int tile = 0; tile < 2; tile++) {   // W2 (K=32, 2 k-tiles), hi+lo
        int k = 16 * tile + k0;
        {
            float a = ew2[k * 32 + m], bb = ew2[(k + 1) * 32 + m];
            encw[512 + tile * 256 + t] = pk_part(a, bb, 0);
            encw[1024 + tile * 256 + t] = pk_part(a, bb, 1);
        }
        {
            float a = dw2[k * 32 + m], bb = dw2[(k + 1) * 32 + m];
            decw[512 + tile * 256 + t] = pk_part(a, bb, 0);
            decw[1024 + tile * 256 + t] = pk_part(a, bb, 1);
        }
        {   // enc W3 (32->2), hi only, rows {0,4}
            float a = 0.f, bb = 0.f;
            if (m == 0 || m == 4) {
                int o = m >> 2;
                a = ew3[k * 2 + o]; bb = ew3[(k + 1) * 2 + o];
            }
            encw[1536 + tile * 256 + t] = pk_part(a, bb, 0);
        }
        {   // dec W3 (32->4), hi only, rows {0,1,4,5}
            float a = 0.f, bb = 0.f;
            if ((m & 3) < 2 && m < 6) {
                int o = (m & 1) + 2 * (m >> 2);
                a = dw3[k * 4 + o]; bb = dw3[(k + 1) * 4 + o];
            }
            decw[1536 + tile * 256 + t] = pk_part(a, bb, 0);
        }
    }
    if (t < 32) {   // bias tabs: index hh*16+r, value bias[row(r,hh)]
        int hh = t >> 4, r = t & 15;
        int row = (r & 3) + 8 * (r >> 2) + 4 * hh;
        ((float*)encw)[2048 + t] = eb2[row];
        ((float*)encw)[2080 + t] = (row == 0) ? eb3[0] : (row == 4) ? eb3[1] : 0.f;
        ((float*)decw)[2048 + t] = db2[row];
        ((float*)decw)[2080 + t] =
            ((row & 3) < 2 && row < 6) ? db3[(row & 1) + 2 * (row >> 2)] : 0.f;
    }
}

// S1 + fused BN stats, 512 threads (R11-verified).
__global__ __launch_bounds__(512) void k_s1(const float* __restrict__ x,
                                            double* __restrict__ stats,
                                            const int* __restrict__ ei,
                                            int* __restrict__ bcnt,
                                            int* __restrict__ bucket_buf) {
    __shared__ int hist[NB];
    __shared__ int base[NB];
    __shared__ int run[NB];
    __shared__ int gbase[NB];
    __shared__ int entries[S1_EPB];
    __shared__ unsigned short bk16[S1_EPB];
    __shared__ int wsum[8];
    __shared__ double smem_bn[8][8];
    int tid = threadIdx.x;

    {   // ---- BN stats slice ----
        int i = blockIdx.x * 512 + tid;
        float4 v = make_float4(0.f, 0.f, 0.f, 0.f);
        if (i < N_NODES) v = ((const float4*)x)[i];
        double a[8];
        a[0] = v.x; a[1] = v.y; a[2] = v.z; a[3] = v.w;
        a[4] = (double)v.x * v.x; a[5] = (double)v.y * v.y;
        a[6] = (double)v.z * v.z; a[7] = (double)v.w * v.w;
        #pragma unroll
        for (int off = 32; off > 0; off >>= 1) {
            #pragma unroll
            for (int j = 0; j < 8; j++) a[j] += __shfl_down(a[j], off);
        }
        int wave = tid >> 6, lane = tid & 63;
        if (lane == 0) {
            #pragma unroll
            for (int j = 0; j < 8; j++) smem_bn[wave][j] = a[j];
        }
        __syncthreads();
        if (tid == 0) {
            #pragma unroll
            for (int j = 0; j < 8; j++) {
                double t2 = 0.0;
                #pragma unroll
                for (int w = 0; w < 8; w++) t2 += smem_bn[w][j];
                atomicAdd(&stats[j], t2);
            }
        }
    }

    // ---- edge binning ----
    int e0 = blockIdx.x * S1_EPB;
    for (int i = tid; i < NB; i += 512) hist[i] = 0;
    __syncthreads();
    #pragma unroll
    for (int k = 0; k < S1_EPB / 512; k++) {
        int e = e0 + k * 512 + tid;
        if (e < N_EDGES) atomicAdd(&hist[ei[N_EDGES + e] >> 7], 1);
    }
    __syncthreads();
    int t4 = tid * 4;
    int h0 = (t4 + 0 < NB) ? hist[t4 + 0] : 0;
    int h1 = (t4 + 1 < NB) ? hist[t4 + 1] : 0;
    int h2 = (t4 + 2 < NB) ? hist[t4 + 2] : 0;
    int h3 = (t4 + 3 < NB) ? hist[t4 + 3] : 0;
    int tsum = h0 + h1 + h2 + h3;
    int lane = tid & 63, wv = tid >> 6;
    int xs = tsum;
    #pragma unroll
    for (int off = 1; off < 64; off <<= 1) {
        int u = __shfl_up(xs, off);
        if (lane >= off) xs += u;
    }
    if (lane == 63) wsum[wv] = xs;
    __syncthreads();
    int wo = 0;
    #pragma unroll
    for (int w = 0; w < 8; w++) if (w < wv) wo += wsum[w];
    int texcl = wo + xs - tsum;
    if (t4 + 0 < NB) base[t4 + 0] = texcl;
    if (t4 + 1 < NB) base[t4 + 1] = texcl + h0;
    if (t4 + 2 < NB) base[t4 + 2] = texcl + h0 + h1;
    if (t4 + 3 < NB) base[t4 + 3] = texcl + h0 + h1 + h2;
    __syncthreads();
    for (int i = tid; i < NB; i += 512) {
        int h = hist[i];
        gbase[i] = i * BSTRIDE + (h ? atomicAdd(&bcnt[i], h) : 0);
        run[i] = base[i];
    }
    __syncthreads();
    #pragma unroll
    for (int k = 0; k < S1_EPB / 512; k++) {
        int e = e0 + k * 512 + tid;
        if (e < N_EDGES) {
            int s = ei[e];
            int d = ei[N_EDGES + e];
            int b = d >> 7;
            int r = atomicAdd(&run[b], 1);   // LDS
            entries[r] = s | ((d & 127) << 17);
            bk16[r] = (unsigned short)b;
        }
    }
    __syncthreads();
    int nloc = min(S1_EPB, N_EDGES - e0);
    for (int idx = tid; idx < nloc; idx += 512) {
        int b = bk16[idx];
        bucket_buf[gbase[b] + (idx - base[b])] = entries[idx];
    }
}

// Fused (BN-folded) encoder 8->32->32->2, all three layers on the matrix pipe.
// R12-verified de-correlated quad assignment Q = sub*384 + (wv+4w) + 12*col.
// R13: swap32 via modeled intrinsic (see above) so the scheduler can overlap
// tile chains.
__global__ __launch_bounds__(256, 4) void k_enc_partial(const float* __restrict__ x,
                                                        const int* __restrict__ bucket_buf,
                                                        const int* __restrict__ bcnt,
                                                        float2* __restrict__ penc,
                                                        int* __restrict__ pcnt,
                                                        const uint* __restrict__ encw) {
    __shared__ float4 xs[128];
    __shared__ float acc0[128], acc1[128];
    __shared__ int lc[128];
    int b = blockIdx.x, sub = blockIdx.y, tid = threadIdx.x;
    int lane = tid & 63, hi = lane >> 5, col = lane & 31, wv = tid >> 6;
    int cb = bcnt[b];
    int node0 = b << 7;

    if (tid < 128) {
        acc0[tid] = 0.f; acc1[tid] = 0.f; lc[tid] = 0;
        int n = node0 + tid;
        if (n >= N_NODES) n = 0;
        xs[tid] = ((const float4*)x)[n];   // raw x (BN folded into weights)
    }
    __syncthreads();

    const u32x4* W4 = (const u32x4*)encw;
    u32x4 w1h  = W4[lane],       w1l  = W4[64 + lane];
    u32x4 w2h0 = W4[128 + lane], w2h1 = W4[192 + lane];
    u32x4 w2l0 = W4[256 + lane], w2l1 = W4[320 + lane];
    u32x4 w30  = W4[384 + lane], w31  = W4[448 + lane];
    const float* tf = (const float*)encw;
    f32x16 b2f;
    {
        const float4* p2 = (const float4*)(tf + 2048 + hi * 16);
        #pragma unroll
        for (int q = 0; q < 4; q++) {
            float4 c = p2[q];
            b2f[4 * q] = c.x; b2f[4 * q + 1] = c.y; b2f[4 * q + 2] = c.z; b2f[4 * q + 3] = c.w;
        }
    }
    float bc0 = tf[2080 + hi * 16] - b2f[0];
    float* accH = hi ? acc1 : acc0;
    uint z = 0;

    int qbase = sub * 384 + wv;          // quad units; windows at +4, +8
    if (4 * qbase < cb) {
        const int4* BB = (const int4*)&bucket_buf[b * BSTRIDE];
        int q0 = qbase + 12 * col;       // this lane's window-0 quad
        int4 qa = BB[q0];
        int4 qb = BB[q0 + 4];
        int4 qc = BB[q0 + 8];
        bool act1 = 4 * (qbase + 4) < cb;
        bool act2 = 4 * (qbase + 8) < cb;

        // slot0 = 4*quad for this lane's window; gate per tile: (slot0+j) < cb
        auto enc_win = [&](const int* ia, const float4* xg, int slot0) {
            #pragma unroll
            for (int j = 0; j < 4; j++) {
                u32x4 xf;
                if (hi == 0) {
                    float4 xi = xs[ia[j]];
                    xf.x = pkh(xi.x, xi.y);
                    xf.y = pkh(xi.z, xi.w);
                    xf.z = pkh(xg[j].x - xi.x, xg[j].y - xi.y);
                    xf.w = pkh(xg[j].z - xi.z, xg[j].w - xi.w);
                } else {
                    xf.x = 0x00003C00u;   // k=8 bias row == 1.0
                    xf.y = 0u; xf.z = 0u; xf.w = 0u;
                }
                f32x16 c = {};
                c = MFMA(w1h, xf, c);
                c = MFMA(w1l, xf, c);
                u32x4 f0, f1;
                repack(c, f0, f1, z);
                f32x16 c2 = MFMA(w2h0, f0, b2f);
                c2 = MFMA(w2h1, f1, c2);
                c2 = MFMA(w2l0, f0, c2);
                c2 = MFMA(w2l1, f1, c2);
                u32x4 e0, e1;
                repack(c2, e0, e1, z);
                f32x16 c3 = MFMA(w30, e0, b2f);   // init garbage cancelled by bc0
                c3 = MFMA(w31, e1, c3);
                float o = fmaxf(c3[0] + bc0, 0.f);
                if ((slot0 + j) < cb) {
                    atomicAdd(&accH[ia[j]], o);
                    if (hi == 0) atomicAdd(&lc[ia[j]], 1);
                }
            }
        };

        int s0[4], s1[4], s2[4], ia0[4], ia1[4], ia2[4];
        float4 xg0[4], xg1[4], xg2[4];
        decode4(qa, s0, ia0);
        if (hi == 0) {
            #pragma unroll
            for (int k = 0; k < 4; k++) xg0[k] = ((const float4*)x)[s0[k]];
        }
        if (act1) {
            decode4(qb, s1, ia1);
            if (hi == 0) {
                #pragma unroll
                for (int k = 0; k < 4; k++) xg1[k] = ((const float4*)x)[s1[k]];
            }
        }
        enc_win(ia0, xg0, 4 * q0);
        if (act2) {
            decode4(qc, s2, ia2);
            if (hi == 0) {
                #pragma unroll
                for (int k = 0; k < 4; k++) xg2[k] = ((const float4*)x)[s2[k]];
            }
        }
        if (act1) enc_win(ia1, xg1, 4 * (q0 + 4));
        if (act2) enc_win(ia2, xg2, 4 * (q0 + 8));
    }
    __syncthreads();
    if (tid < 128) {
        int pb = b * NSUB + sub;
        penc[pb * 128 + tid] = make_float2(acc0[tid], acc1[tid]);
        pcnt[pb * 128 + tid] = lc[tid];
    }
}

// sum NSUB chunk-partials per node -> agg1 (mean) + invcnt
__global__ __launch_bounds__(256) void k_reduce_enc_p(const float2* __restrict__ penc,
                                                      const int* __restrict__ pcnt,
                                                      float2* __restrict__ agg1,
                                                      float* __restrict__ invcnt) {
    int i = blockIdx.x * 256 + threadIdx.x;
    if (i >= N_NODES) return;
    int b = i >> 7, l = i & 127;
    float a0 = 0.f, a1 = 0.f;
    int c = 0;
    #pragma unroll
    for (int sub = 0; sub < NSUB; sub++) {
        int idx = (b * NSUB + sub) * 128 + l;
        float2 p = penc[idx];
        a0 += p.x; a1 += p.y;
        c += pcnt[idx];
    }
    float ic = 1.0f / (float)(c > 1 ? c : 1);
    invcnt[i] = ic;
    agg1[i] = make_float2(a0 * ic, a1 * ic);
}

// Fused decoder 4->32->32->4, same de-correlated quad assignment.
// Split atomics: hi=0 -> out0,1; hi=1 -> out2,3 (W3 rows 0,1,4,5).
__global__ __launch_bounds__(256, 4) void k_dec_partial(const float2* __restrict__ henc,
                                                        const int* __restrict__ bucket_buf,
                                                        const int* __restrict__ bcnt,
                                                        float4* __restrict__ pdec,
                                                        const uint* __restrict__ decw) {
    __shared__ float2 hld[128];
    __shared__ float a0s[128], a1s[128], a2s[128], a3s[128];
    int b = blockIdx.x, sub = blockIdx.y, tid = threadIdx.x;
    int lane = tid & 63, hi = lane >> 5, col = lane & 31, wv = tid >> 6;
    int cb = bcnt[b];
    int node0 = b << 7;

    if (tid < 128) {
        a0s[tid] = 0.f; a1s[tid] = 0.f; a2s[tid] = 0.f; a3s[tid] = 0.f;
        int n = node0 + tid;
        if (n >= N_NODES) n = 0;
        hld[tid] = henc[n];
    }
    __syncthreads();

    const u32x4* W4 = (const u32x4*)decw;
    u32x4 w1h  = W4[lane],       w1l  = W4[64 + lane];
    u32x4 v2h0 = W4[128 + lane], v2h1 = W4[192 + lane];
    u32x4 v2l0 = W4[256 + lane], v2l1 = W4[320 + lane];
    u32x4 w30  = W4[384 + lane], w31  = W4[448 + lane];
    const float* tf = (const float*)decw;
    f32x16 b2f;
    {
        const float4* p2 = (const float4*)(tf + 2048 + hi * 16);
        #pragma unroll
        for (int q = 0; q < 4; q++) {
            float4 c = p2[q];
            b2f[4 * q] = c.x; b2f[4 * q + 1] = c.y; b2f[4 * q + 2] = c.z; b2f[4 * q + 3] = c.w;
        }
    }
    float bc0 = tf[2080 + hi * 16 + 0] - b2f[0];
    float bc1 = tf[2080 + hi * 16 + 1] - b2f[1];
    float* accA = hi ? a2s : a0s;
    float* accB = hi ? a3s : a1s;
    uint z = 0;

    int qbase = sub * 384 + wv;
    if (4 * qbase < cb) {
        const int4* BB = (const int4*)&bucket_buf[b * BSTRIDE];
        int q0 = qbase + 12 * col;
        int4 qa = BB[q0];
        int4 qb = BB[q0 + 4];
        int4 qc = BB[q0 + 8];
        bool act1 = 4 * (qbase + 4) < cb;
        bool act2 = 4 * (qbase + 8) < cb;

        auto dec_win = [&](const int* ia, const float2* hj, int slot0) {
            #pragma unroll
            for (int j = 0; j < 4; j++) {
                u32x4 xf;
                if (hi == 0) {
                    float2 h2 = hld[ia[j]];
                    xf.x = pkh(h2.x, h2.y);
                    xf.y = pkh(hj[j].x - h2.x, hj[j].y - h2.y);
                    xf.z = 0x00003C00u;   // k=4 bias row == 1.0
                    xf.w = 0u;
                } else {
                    xf.x = 0u; xf.y = 0u; xf.z = 0u; xf.w = 0u;
                }
                f32x16 c = {};
                c = MFMA(w1h, xf, c);
                c = MFMA(w1l, xf, c);
                u32x4 f0, f1;
                repack(c, f0, f1, z);
                f32x16 c2 = MFMA(v2h0, f0, b2f);
                c2 = MFMA(v2h1, f1, c2);
                c2 = MFMA(v2l0, f0, c2);
                c2 = MFMA(v2l1, f1, c2);
                u32x4 e0, e1;
                repack(c2, e0, e1, z);
                f32x16 c3 = MFMA(w30, e0, b2f);
                c3 = MFMA(w31, e1, c3);
                float o0 = c3[0] + bc0;
                float o1 = c3[1] + bc1;
                if ((slot0 + j) < cb) {
                    atomicAdd(&accA[ia[j]], o0);
                    atomicAdd(&accB[ia[j]], o1);
                }
            }
        };

        int s0[4], s1[4], s2[4], ia0[4], ia1[4], ia2[4];
        float2 hg0[4], hg1[4], hg2[4];
        decode4(qa, s0, ia0);
        if (hi == 0) {
            #pragma unroll
            for (int k = 0; k < 4; k++) hg0[k] = henc[s0[k]];
        }
        if (act1) {
            decode4(qb, s1, ia1);
            if (hi == 0) {
                #pragma unroll
                for (int k = 0; k < 4; k++) hg1[k] = henc[s1[k]];
            }
        }
        dec_win(ia0, hg0, 4 * q0);
        if (act2) {
            decode4(qc, s2, ia2);
            if (hi == 0) {
                #pragma unroll
                for (int k = 0; k < 4; k++) hg2[k] = henc[s2[k]];
            }
        }
        if (act1) dec_win(ia1, hg1, 4 * (q0 + 4));
        if (act2) dec_win(ia2, hg2, 4 * (q0 + 8));
    }
    __syncthreads();
    if (tid < 128) {
        int pb = b * NSUB + sub;
        pdec[pb * 128 + tid] = make_float4(a0s[tid], a1s[tid], a2s[tid], a3s[tid]);
    }
}

// sum NSUB chunk-partials per node -> final output (mean)
__global__ __launch_bounds__(256) void k_reduce_dec_p(const float4* __restrict__ pdec,
                                                      const float* __restrict__ invcnt,
                                                      float4* __restrict__ out) {
    int i = blockIdx.x * 256 + threadIdx.x;
    if (i >= N_NODES) return;
    int b = i >> 7, l = i & 127;
    float a0 = 0.f, a1 = 0.f, a2 = 0.f, a3 = 0.f;
    #pragma unroll
    for (int sub = 0; sub < NSUB; sub++) {
        float4 p = pdec[(b * NSUB + sub) * 128 + l];
        a0 += p.x; a1 += p.y; a2 += p.z; a3 += p.w;
    }
    float ic = invcnt[i];
    out[i] = make_float4(a0 * ic, a1 * ic, a2 * ic, a3 * ic);
}

extern "C" void kernel_launch(void* const* d_in, const int* in_sizes, int n_in,
                              void* d_out, int out_size, void* d_ws, size_t ws_size,
                              hipStream_t stream) {
    const float* x    = (const float*)d_in[0];
    const int*   ei   = (const int*)d_in[1];
    const float* bn_w = (const float*)d_in[2];
    const float* bn_b = (const float*)d_in[3];
    const float* ew1  = (const float*)d_in[4];
    const float* eb1  = (const float*)d_in[5];
    const float* ew2  = (const float*)d_in[6];
    const float* eb2  = (const float*)d_in[7];
    const float* ew3  = (const float*)d_in[8];
    const float* eb3  = (const float*)d_in[9];
    const float* dw1  = (const float*)d_in[10];
    const float* db1  = (const float*)d_in[11];
    const float* dw2  = (const float*)d_in[12];
    const float* db2  = (const float*)d_in[13];
    const float* dw3  = (const float*)d_in[14];
    const float* db3  = (const float*)d_in[15];

    char* ws = (char*)d_ws;
    double* stats      = (double*)(ws + OFF_STATS);
    int*    bcnt       = (int*)(ws + OFF_BCNT);
    float*  invcnt     = (float*)(ws + OFF_INVCNT);
    float2* agg1       = (float2*)(ws + OFF_AGG1);
    uint*   decw       = (uint*)(ws + OFF_DECW);
    int*    bucket_buf = (int*)(ws + OFF_BUCKET);
    float2* penc       = (float2*)(ws + OFF_PENC);
    int*    pcnt       = (int*)(ws + OFF_PCNT);
    float4* pdec       = (float4*)(ws + OFF_PDEC);
    uint*   encw       = (uint*)(ws + OFF_ENCW);
    float4* out        = (float4*)d_out;

    // zero: stats + bucket counts, contiguous [0, 5120)
    hipMemsetAsync(ws, 0, 5120, stream);

    k_s1<<<S1_BLOCKS, 512, 0, stream>>>(x, stats, ei, bcnt, bucket_buf);
    k_prep<<<1, 256, 0, stream>>>(stats, bn_w, bn_b, ew1, eb1, ew2, eb2, ew3, eb3,
                                  dw1, db1, dw2, db2, dw3, db3, encw, decw);
    k_enc_partial<<<dim3(NB, NSUB), 256, 0, stream>>>(x, bucket_buf, bcnt,
                                                      penc, pcnt, encw);
    k_reduce_enc_p<<<NODE_BLOCKS, 256, 0, stream>>>(penc, pcnt, agg1, invcnt);
    k_dec_partial<<<dim3(NB, NSUB), 256, 0, stream>>>(agg1, bucket_buf, bcnt, pdec, decw);
    k_reduce_dec_p<<<NODE_BLOCKS, 256, 0, stream>>>(pdec, invcnt, out);
}